// Round 3
// baseline (226.510 us; speedup 1.0000x reference)
//
#include <hip/hip_runtime.h>

#define DIM 16
#define HID 256
#define NSTEPS 10
#define TILE_B 32
#define NTHR 1024
#define LSH 264      // bf16 LDS row stride, multiple of 8 shorts (16 B) for aligned bf16x8 reads.
                     // Swizzle convention everywhere: stored col' = col ^ (16 * bit3(row)).
                     // R18: phase-2 operand swap. A/B lane layouts of 16x16x32 are symmetric, so
                     // mfma(breg, af, cc) transposes C to [n][b] (batch in LANES) with IDENTICAL
                     // LDS reads and breg. This converts the h2/d2 epilogue from 16 b16 scatters
                     // to 8 packed b64 writes, the divergence dot from 16 u16 gathers + 32 shfl
                     // to 4 b64 reads + 4 shfl (shfl = ds_bpermute = LDS pipe, the real cost).

typedef __attribute__((ext_vector_type(8))) short bf16x8;
typedef __attribute__((ext_vector_type(4))) float f32x4;
typedef __attribute__((ext_vector_type(2))) unsigned int u32x2;

__device__ __forceinline__ unsigned short f2bf(float f) {
    unsigned u = __float_as_uint(f);
    u += 0x7fff + ((u >> 16) & 1);          // RNE
    return (unsigned short)(u >> 16);
}
__device__ __forceinline__ float bfw_lo(unsigned u) { return __uint_as_float(u << 16); }
__device__ __forceinline__ float bfw_hi(unsigned u) { return __uint_as_float(u & 0xffff0000u); }
__device__ __forceinline__ unsigned packtr(float a, float b) {   // [bf16(b):bf16(a)], trunc
    return __builtin_amdgcn_perm(__float_as_uint(b), __float_as_uint(a), 0x07060302u);
}
__device__ __forceinline__ void silu_both(float x, float& h, float& d) {
    float s = __builtin_amdgcn_rcpf(1.0f + __expf(-x));
    h = x * s;
    d = fmaf(h, 1.0f - s, s);               // silu' = s + h*(1-s)
}

// w2t[n][j] = bf16(W2[j][n]);  mt[n][j] = bf16(M[j][n]), M[j][n] = W2[j][n]*sum_i W1[i][j]*W3[n][i]
__global__ void cnf_setup(const float* __restrict__ W1, const float* __restrict__ W2,
                          const float* __restrict__ W3,
                          unsigned short* __restrict__ w2t, unsigned short* __restrict__ mt) {
    const int j = blockIdx.x;
    const int n = threadIdx.x;
    float g = 0.0f;
#pragma unroll
    for (int i = 0; i < DIM; ++i) g = fmaf(W1[i * HID + j], W3[n * DIM + i], g);
    const float w2 = W2[j * HID + n];
    w2t[n * HID + j] = f2bf(w2);
    mt [n * HID + j] = f2bf(w2 * g);
}

__global__ __launch_bounds__(NTHR, 4) void cnf_main(
    const float* __restrict__ x,
    const float* __restrict__ W1, const float* __restrict__ b1,
    const float* __restrict__ b2, const float* __restrict__ b3,
    const unsigned short* __restrict__ w2t, const unsigned short* __restrict__ mt,
    const float* __restrict__ W3, float* __restrict__ out)
{
    __shared__ unsigned short zb[TILE_B][40];   // z-ext^T rows: 0..15 = z, 16 = t, 17 = 1.0, 18..31 = 0
    __shared__ unsigned short w3t[DIM][LSH];    // w3t[i][n] = W3[n][i]
    __shared__ unsigned short h1s[TILE_B][LSH]; // [b][n ^ 16*bit3(b)]
    __shared__ unsigned short d1s[TILE_B][LSH];
    __shared__ unsigned short h2s[TILE_B][LSH];
    __shared__ unsigned short d2s[TILE_B][LSH];
    __shared__ float divp[8][TILE_B];

    const int tid  = (int)threadIdx.x;
    const int lane = tid & 63;
    const int wv   = tid >> 6;            // 0..15
    const int g    = lane >> 4;           // quad 0..3
    const int r    = lane & 15;
    const int g8   = g * 8;
    const int b0   = (int)blockIdx.x * TILE_B;
    const int swr  = ((r >> 3) & 1) << 4; // swizzle when row = bt*16+r (row bit3 = r bit3)
    const int goff = g8 ^ swr;            // phase-2/3 read col offset
    const int n0w  = (wv & 7) * 32;

    // ---- phase-2 operand fragments (constant, in registers; R5 lesson: full unroll).
    // As A-operand: lane (r,g) holds rows n = n0w + nt*16 + r, k-slice g*8 (+ k_step*32).
    bf16x8 breg[8][2];
    {
        const unsigned short* Bg = (wv < 8) ? w2t : mt;
#pragma unroll
        for (int k = 0; k < 8; ++k)
#pragma unroll
            for (int nt = 0; nt < 2; ++nt)
                breg[k][nt] = *(const bf16x8*)(Bg + (n0w + nt * 16 + r) * HID + k * 32 + g8);
    }

    // ---- phase-1 A-fragment (per-wave n-cols wv*16..+15): W1ext^T, b1 and t-row folded as K=16/17
    bf16x8 w1f;
    {
        const int n = wv * 16 + r;
#pragma unroll
        for (int e = 0; e < 8; ++e) {
            const int k = g8 + e;
            float v = 0.0f;
            if (k < 17)       v = W1[k * HID + n];   // k=16 is the t-row of W1
            else if (k == 17) v = b1[n];
            w1f[e] = (short)f2bf(v);
        }
    }

    // ---- per-thread bias preloads: b2 along the q (n) axis now ----
    const f32x4 b2q0 = *(const f32x4*)&b2[n0w + 4 * g];
    const f32x4 b2q1 = *(const f32x4*)&b2[n0w + 16 + 4 * g];
    float b3q[4] = {0, 0, 0, 0};
    if (wv < 2)
#pragma unroll
        for (int q = 0; q < 4; ++q) b3q[q] = b3[4 * g + q];

    // ---- update-wave (0/1) z-state: lane (r,g) holds z[b=wv*16+r][i=4g+q], fp32 ----
    float zb4[4] = {0, 0, 0, 0}, za4[4] = {0, 0, 0, 0};
    if (wv < 2) {
        const f32x4 xv = *(const f32x4*)&x[(b0 + wv * 16 + r) * DIM + 4 * g];
#pragma unroll
        for (int q = 0; q < 4; ++q) zb4[q] = xv[q];
        u32x2 pz = { (unsigned)f2bf(zb4[0]) | ((unsigned)f2bf(zb4[1]) << 16),
                     (unsigned)f2bf(zb4[2]) | ((unsigned)f2bf(zb4[3]) << 16) };
        *(u32x2*)&zb[wv * 16 + r][4 * g] = pz;
    }
    if (tid < TILE_B) {      // ext cols: t(=0 for stage 0), one, zeros
#pragma unroll
        for (int c = 16; c < 32; ++c)
            zb[tid][c] = (c == 17) ? (unsigned short)0x3F80 : (unsigned short)0;
    }
    if (tid < 512) {         // w3t[i][n] = W3[n][i]
        const int n = tid >> 5, k0 = (tid & 31) * 8;
#pragma unroll
        for (int j = 0; j < 8; ++j) w3t[n][k0 + j] = f2bf(W3[(k0 + j) * DIM + n]);
    }

    float lacc = 0.0f, logp = 0.0f;
    const float dt = 0.1f, dt6 = dt / 6.0f;

    for (int it = 0; it < NSTEPS * 4; ++it) {
        const int s = it & 3;
        const float wst = (s == 1 || s == 2) ? 2.0f : 1.0f;
        __syncthreads();   // B1: zb (z + t col) and prev-stage divp ready

        // ---------- deferred logp update for the PREVIOUS stage (wave 8) ----------
        if (wv == 8 && lane < TILE_B && it) {
            const int ps = (it + 3) & 3;
            const float pw = (ps == 1 || ps == 2) ? 2.0f : 1.0f;
            float dv = 0.0f;
#pragma unroll
            for (int w = 0; w < 8; ++w) dv += divp[w][lane];
            lacc = fmaf(-pw, dv, lacc);
            if (ps == 3) { logp = fmaf(dt6, lacc, logp); lacc = 0.0f; }
        }

        // ---------- phase 1 (all 16 waves, transposed): pre1^T[n][b] = W1ext^T @ zext^T
        //            -> h1,d1 packed b64 stores ----------
        {
#pragma unroll
            for (int bt = 0; bt < 2; ++bt) {
                const bf16x8 bz = *(const bf16x8*)&zb[bt * 16 + r][g8];
                f32x4 c = {0.f, 0.f, 0.f, 0.f};
                c = __builtin_amdgcn_mfma_f32_16x16x32_bf16(w1f, bz, c, 0, 0, 0);
                float h[4], d[4];
#pragma unroll
                for (int q = 0; q < 4; ++q) silu_both(c[q], h[q], d[q]);
                const int row = bt * 16 + r;
                const int col = (wv * 16 + 4 * g) ^ swr;
                u32x2 hv  = { packtr(h[0], h[1]), packtr(h[2], h[3]) };
                u32x2 dv2 = { packtr(d[0], d[1]), packtr(d[2], d[3]) };
                *(u32x2*)&h1s[row][col] = hv;
                *(u32x2*)&d1s[row][col] = dv2;
            }
        }
        __syncthreads();   // B2: h1/d1 ready

        // ---------- phase 2 (operand-swapped MFMA): C[n][b], batch in lanes.
        //            A = breg (W2^T / M^T rows), B = h1/d1 rows -- LDS reads unchanged ----------
        f32x4 cc[2][2];    // [nt][bt]
        {
            const unsigned short (*aT)[LSH] = (wv < 8) ? h1s : d1s;
#pragma unroll
            for (int a = 0; a < 2; ++a)
#pragma unroll
                for (int b = 0; b < 2; ++b) cc[a][b] = (f32x4){0.f, 0.f, 0.f, 0.f};
#pragma unroll
            for (int k = 0; k < 8; ++k) {
                bf16x8 af[2];
#pragma unroll
                for (int bt = 0; bt < 2; ++bt)
                    af[bt] = *(const bf16x8*)&aT[bt * 16 + r][k * 32 + goff];
#pragma unroll
                for (int nt = 0; nt < 2; ++nt)
#pragma unroll
                    for (int bt = 0; bt < 2; ++bt)
                        cc[nt][bt] = __builtin_amdgcn_mfma_f32_16x16x32_bf16(breg[k][nt], af[bt], cc[nt][bt], 0, 0, 0);
            }
        }
        // no barrier: h2/d2 go to separate buffers
        if (wv < 8) {   // h-wave epilogue: silu -> h2s/d2s, packed b64 stores (batch row = lane r)
#pragma unroll
            for (int nt = 0; nt < 2; ++nt) {
                const f32x4 bb = nt ? b2q1 : b2q0;
#pragma unroll
                for (int bt = 0; bt < 2; ++bt) {
                    float h[4], d[4];
#pragma unroll
                    for (int q = 0; q < 4; ++q) silu_both(cc[nt][bt][q] + bb[q], h[q], d[q]);
                    const int row = bt * 16 + r;
                    const int col = (n0w + nt * 16 + 4 * g) ^ swr;
                    u32x2 hv  = { packtr(h[0], h[1]), packtr(h[2], h[3]) };
                    u32x2 dv2 = { packtr(d[0], d[1]), packtr(d[2], d[3]) };
                    *(u32x2*)&h2s[row][col] = hv;
                    *(u32x2*)&d2s[row][col] = dv2;
                }
            }
        }
        __syncthreads();   // B4: h2/d2 ready

        if (wv < 2) {
            // ---------- phase 3 (operand-swapped): fz^T[i][b] = W3^T @ h2^T, K=256,
            //            dual accumulator chains; in-register RK4; packed zb write ----------
            const unsigned short* h2row = &h2s[wv * 16 + r][0];
            const unsigned short* w3row = &w3t[r][0];
            f32x4 c3a = {0.f, 0.f, 0.f, 0.f}, c3b = {0.f, 0.f, 0.f, 0.f};
#pragma unroll
            for (int kt = 0; kt < 8; ++kt) {
                const bf16x8 a3  = *(const bf16x8*)(w3row + kt * 32 + g8);
                const bf16x8 bf3 = *(const bf16x8*)(h2row + kt * 32 + goff);
                if (kt & 1) c3b = __builtin_amdgcn_mfma_f32_16x16x32_bf16(a3, bf3, c3b, 0, 0, 0);
                else        c3a = __builtin_amdgcn_mfma_f32_16x16x32_bf16(a3, bf3, c3a, 0, 0, 0);
            }
            const float coef = (s == 2) ? dt : 0.5f * dt;
            float zn[4];
#pragma unroll
            for (int q = 0; q < 4; ++q) {
                const float fz = c3a[q] + c3b[q] + b3q[q];
                za4[q] = fmaf(wst, fz, za4[q]);
                if (s < 3) zn[q] = fmaf(coef, fz, zb4[q]);
                else { zb4[q] = fmaf(dt6, za4[q], zb4[q]); zn[q] = zb4[q]; za4[q] = 0.0f; }
            }
            u32x2 pz = { (unsigned)f2bf(zn[0]) | ((unsigned)f2bf(zn[1]) << 16),
                         (unsigned)f2bf(zn[2]) | ((unsigned)f2bf(zn[3]) << 16) };
            *(u32x2*)&zb[wv * 16 + r][4 * g] = pz;
            if (wv == 0 && lane < TILE_B) {      // publish t for next stage
                const int it1 = it + 1;
                const int s1 = it1 & 3;
                const float t1 = dt * (float)(it1 >> 2) + ((s1 == 0) ? 0.0f : (s1 == 3) ? dt : 0.5f * dt);
                zb[lane][16] = f2bf(t1);
            }
        } else if (wv >= 8) {
            // ---------- v-waves: div_b = sum_n d2[b][n]*v[n][b]; batch lane-local now.
            //            4 packed b64 reads + 16 fma + 2 shfl per p ----------
            float p0 = 0.0f, p1 = 0.0f;
#pragma unroll
            for (int nt = 0; nt < 2; ++nt)
#pragma unroll
                for (int bt = 0; bt < 2; ++bt) {
                    const int row = bt * 16 + r;
                    const int col = (n0w + nt * 16 + 4 * g) ^ swr;
                    const u32x2 du = *(const u32x2*)&d2s[row][col];
                    float pp = (bt == 0) ? p0 : p1;
                    pp = fmaf(bfw_lo(du[0]), cc[nt][bt][0], pp);
                    pp = fmaf(bfw_hi(du[0]), cc[nt][bt][1], pp);
                    pp = fmaf(bfw_lo(du[1]), cc[nt][bt][2], pp);
                    pp = fmaf(bfw_hi(du[1]), cc[nt][bt][3], pp);
                    if (bt == 0) p0 = pp; else p1 = pp;
                }
            p0 += __shfl_xor(p0, 16, 64);
            p0 += __shfl_xor(p0, 32, 64);
            p1 += __shfl_xor(p1, 16, 64);
            p1 += __shfl_xor(p1, 32, 64);
            if (g == 0) divp[wv - 8][r]      = p0;
            if (g == 1) divp[wv - 8][16 + r] = p1;
        }
        // (loop-top barrier covers zb, t-col and divp)
    }

    // ---------- epilogue ----------
    __syncthreads();
    if (wv == 8 && lane < TILE_B) {   // flush last stage (s=3, weight 1) and publish logp
        float dv = 0.0f;
#pragma unroll
        for (int w = 0; w < 8; ++w) dv += divp[w][lane];
        lacc -= dv;
        logp = fmaf(dt6, lacc, logp);
        divp[0][lane] = logp;
    }
    __syncthreads();
    if (wv < 2) {
        float ss = zb4[0] * zb4[0] + zb4[1] * zb4[1] + zb4[2] * zb4[2] + zb4[3] * zb4[3];
        ss += __shfl_xor(ss, 16, 64);
        ss += __shfl_xor(ss, 32, 64);
        if (g == 0) {
            const int row = wv * 16 + r;
            out[b0 + row] = -0.5f * (ss + (float)DIM * 1.8378770664093453f) - divp[0][row];
        }
    }
}

extern "C" void kernel_launch(void* const* d_in, const int* in_sizes, int n_in,
                              void* d_out, int out_size, void* d_ws, size_t ws_size,
                              hipStream_t stream) {
    (void)in_sizes; (void)n_in; (void)out_size; (void)ws_size;
    const float* x  = (const float*)d_in[0];
    const float* W1 = (const float*)d_in[1];
    const float* b1 = (const float*)d_in[2];
    const float* W2 = (const float*)d_in[3];
    const float* b2 = (const float*)d_in[4];
    const float* W3 = (const float*)d_in[5];
    const float* b3 = (const float*)d_in[6];
    unsigned short* w2t = (unsigned short*)d_ws;               // 128 KB
    unsigned short* mt  = w2t + HID * HID;                     // 128 KB

    cnf_setup<<<HID, HID, 0, stream>>>(W1, W2, W3, w2t, mt);
    cnf_main<<<8192 / TILE_B, NTHR, 0, stream>>>(x, W1, b1, b2, b3, w2t, mt, W3, (float*)d_out);
}

// Round 4
// 192.931 us; speedup vs baseline: 1.1741x; 1.1741x over previous
//
#include <hip/hip_runtime.h>

#define DIM 16
#define HID 256
#define NSTEPS 10
#define TILE_B 32
#define NTHR 1024
#define LSH 264      // bf16 LDS row stride, multiple of 8 shorts (16 B) for aligned bf16x8 reads.
                     // Swizzle convention everywhere: stored col' = col ^ (16 * bit3(row)).
                     // R19: R18 structure (operand-swapped phase 2: C=[n][b], batch in lanes;
                     // packed b64 epilogue + lane-local divergence dot) with the REGISTER SPILLS
                     // removed: R18's persistent f32x4 b2q/b3q (12 VGPRs) pushed the 16-wave
                     // 128-VGPR/wave cap and spilled to scratch (WRITE_SIZE 32KB->17MB, +10us in
                     // the serial phase-3 path). Biases now live in LDS (b2l/b3l) and are re-read
                     // each stage; an opaque zero (asm "+v") blocks loop-invariant hoisting so the
                     // allocator can't re-materialize them as persistent registers.

typedef __attribute__((ext_vector_type(8))) short bf16x8;
typedef __attribute__((ext_vector_type(4))) float f32x4;
typedef __attribute__((ext_vector_type(2))) unsigned int u32x2;

__device__ __forceinline__ unsigned short f2bf(float f) {
    unsigned u = __float_as_uint(f);
    u += 0x7fff + ((u >> 16) & 1);          // RNE
    return (unsigned short)(u >> 16);
}
__device__ __forceinline__ float bfw_lo(unsigned u) { return __uint_as_float(u << 16); }
__device__ __forceinline__ float bfw_hi(unsigned u) { return __uint_as_float(u & 0xffff0000u); }
__device__ __forceinline__ unsigned packtr(float a, float b) {   // [bf16(b):bf16(a)], trunc
    return __builtin_amdgcn_perm(__float_as_uint(b), __float_as_uint(a), 0x07060302u);
}
__device__ __forceinline__ void silu_both(float x, float& h, float& d) {
    float s = __builtin_amdgcn_rcpf(1.0f + __expf(-x));
    h = x * s;
    d = fmaf(h, 1.0f - s, s);               // silu' = s + h*(1-s)
}

// w2t[n][j] = bf16(W2[j][n]);  mt[n][j] = bf16(M[j][n]), M[j][n] = W2[j][n]*sum_i W1[i][j]*W3[n][i]
__global__ void cnf_setup(const float* __restrict__ W1, const float* __restrict__ W2,
                          const float* __restrict__ W3,
                          unsigned short* __restrict__ w2t, unsigned short* __restrict__ mt) {
    const int j = blockIdx.x;
    const int n = threadIdx.x;
    float g = 0.0f;
#pragma unroll
    for (int i = 0; i < DIM; ++i) g = fmaf(W1[i * HID + j], W3[n * DIM + i], g);
    const float w2 = W2[j * HID + n];
    w2t[n * HID + j] = f2bf(w2);
    mt [n * HID + j] = f2bf(w2 * g);
}

__global__ __launch_bounds__(NTHR, 4) void cnf_main(
    const float* __restrict__ x,
    const float* __restrict__ W1, const float* __restrict__ b1,
    const float* __restrict__ b2, const float* __restrict__ b3,
    const unsigned short* __restrict__ w2t, const unsigned short* __restrict__ mt,
    const float* __restrict__ W3, float* __restrict__ out)
{
    __shared__ unsigned short zb[TILE_B][40];   // z-ext^T rows: 0..15 = z, 16 = t, 17 = 1.0, 18..31 = 0
    __shared__ unsigned short w3t[DIM][LSH];    // w3t[i][n] = W3[n][i]
    __shared__ unsigned short h1s[TILE_B][LSH]; // [b][n ^ 16*bit3(b)]
    __shared__ unsigned short d1s[TILE_B][LSH];
    __shared__ unsigned short h2s[TILE_B][LSH];
    __shared__ unsigned short d2s[TILE_B][LSH];
    __shared__ float divp[8][TILE_B];
    __shared__ float b2l[HID];
    __shared__ float b3l[DIM];

    const int tid  = (int)threadIdx.x;
    const int lane = tid & 63;
    const int wv   = tid >> 6;            // 0..15
    const int g    = lane >> 4;           // quad 0..3
    const int r    = lane & 15;
    const int g8   = g * 8;
    const int b0   = (int)blockIdx.x * TILE_B;
    const int swr  = ((r >> 3) & 1) << 4; // swizzle when row = bt*16+r (row bit3 = r bit3)
    const int goff = g8 ^ swr;            // phase-2/3 read col offset
    const int n0w  = (wv & 7) * 32;

    // ---- phase-2 operand fragments (constant, in registers; R5 lesson: full unroll).
    // As A-operand: lane (r,g) holds rows n = n0w + nt*16 + r, k-slice g*8 (+ k_step*32).
    bf16x8 breg[8][2];
    {
        const unsigned short* Bg = (wv < 8) ? w2t : mt;
#pragma unroll
        for (int k = 0; k < 8; ++k)
#pragma unroll
            for (int nt = 0; nt < 2; ++nt)
                breg[k][nt] = *(const bf16x8*)(Bg + (n0w + nt * 16 + r) * HID + k * 32 + g8);
    }

    // ---- phase-1 A-fragment (per-wave n-cols wv*16..+15): W1ext^T, b1 and t-row folded as K=16/17
    bf16x8 w1f;
    {
        const int n = wv * 16 + r;
#pragma unroll
        for (int e = 0; e < 8; ++e) {
            const int k = g8 + e;
            float v = 0.0f;
            if (k < 17)       v = W1[k * HID + n];   // k=16 is the t-row of W1
            else if (k == 17) v = b1[n];
            w1f[e] = (short)f2bf(v);
        }
    }

    // ---- update-wave (0/1) z-state: lane (r,g) holds z[b=wv*16+r][i=4g+q], fp32 ----
    float zb4[4] = {0, 0, 0, 0}, za4[4] = {0, 0, 0, 0};
    if (wv < 2) {
        const f32x4 xv = *(const f32x4*)&x[(b0 + wv * 16 + r) * DIM + 4 * g];
#pragma unroll
        for (int q = 0; q < 4; ++q) zb4[q] = xv[q];
        u32x2 pz = { (unsigned)f2bf(zb4[0]) | ((unsigned)f2bf(zb4[1]) << 16),
                     (unsigned)f2bf(zb4[2]) | ((unsigned)f2bf(zb4[3]) << 16) };
        *(u32x2*)&zb[wv * 16 + r][4 * g] = pz;
    }
    if (tid < TILE_B) {      // ext cols: t(=0 for stage 0), one, zeros
#pragma unroll
        for (int c = 16; c < 32; ++c)
            zb[tid][c] = (c == 17) ? (unsigned short)0x3F80 : (unsigned short)0;
    }
    if (tid < 512) {         // w3t[i][n] = W3[n][i]
        const int n = tid >> 5, k0 = (tid & 31) * 8;
#pragma unroll
        for (int j = 0; j < 8; ++j) w3t[n][k0 + j] = f2bf(W3[(k0 + j) * DIM + n]);
    }
    if (tid < HID) b2l[tid] = b2[tid];   // biases live in LDS, not registers (R19)
    if (tid < DIM) b3l[tid] = b3[tid];

    float lacc = 0.0f, logp = 0.0f;
    const float dt = 0.1f, dt6 = dt / 6.0f;

    for (int it = 0; it < NSTEPS * 4; ++it) {
        const int s = it & 3;
        const float wst = (s == 1 || s == 2) ? 2.0f : 1.0f;
        int opq = 0;
        asm volatile("" : "+v"(opq));    // opaque 0: blocks hoisting of per-stage bias reloads
        __syncthreads();   // B1: zb (z + t col) and prev-stage divp ready

        // ---------- deferred logp update for the PREVIOUS stage (wave 8) ----------
        if (wv == 8 && lane < TILE_B && it) {
            const int ps = (it + 3) & 3;
            const float pw = (ps == 1 || ps == 2) ? 2.0f : 1.0f;
            float dv = 0.0f;
#pragma unroll
            for (int w = 0; w < 8; ++w) dv += divp[w][lane];
            lacc = fmaf(-pw, dv, lacc);
            if (ps == 3) { logp = fmaf(dt6, lacc, logp); lacc = 0.0f; }
        }

        // ---------- phase 1 (all 16 waves, transposed): pre1^T[n][b] = W1ext^T @ zext^T
        //            -> h1,d1 packed b64 stores ----------
        {
#pragma unroll
            for (int bt = 0; bt < 2; ++bt) {
                const bf16x8 bz = *(const bf16x8*)&zb[bt * 16 + r][g8];
                f32x4 c = {0.f, 0.f, 0.f, 0.f};
                c = __builtin_amdgcn_mfma_f32_16x16x32_bf16(w1f, bz, c, 0, 0, 0);
                float h[4], d[4];
#pragma unroll
                for (int q = 0; q < 4; ++q) silu_both(c[q], h[q], d[q]);
                const int row = bt * 16 + r;
                const int col = (wv * 16 + 4 * g) ^ swr;
                u32x2 hv  = { packtr(h[0], h[1]), packtr(h[2], h[3]) };
                u32x2 dv2 = { packtr(d[0], d[1]), packtr(d[2], d[3]) };
                *(u32x2*)&h1s[row][col] = hv;
                *(u32x2*)&d1s[row][col] = dv2;
            }
        }
        __syncthreads();   // B2: h1/d1 ready

        // ---------- phase 2 (operand-swapped MFMA): C[n][b], batch in lanes.
        //            A = breg (W2^T / M^T rows), B = h1/d1 rows -- LDS reads unchanged ----------
        f32x4 cc[2][2];    // [nt][bt]
        {
            const unsigned short (*aT)[LSH] = (wv < 8) ? h1s : d1s;
#pragma unroll
            for (int a = 0; a < 2; ++a)
#pragma unroll
                for (int b = 0; b < 2; ++b) cc[a][b] = (f32x4){0.f, 0.f, 0.f, 0.f};
#pragma unroll
            for (int k = 0; k < 8; ++k) {
                bf16x8 af[2];
#pragma unroll
                for (int bt = 0; bt < 2; ++bt)
                    af[bt] = *(const bf16x8*)&aT[bt * 16 + r][k * 32 + goff];
#pragma unroll
                for (int nt = 0; nt < 2; ++nt)
#pragma unroll
                    for (int bt = 0; bt < 2; ++bt)
                        cc[nt][bt] = __builtin_amdgcn_mfma_f32_16x16x32_bf16(breg[k][nt], af[bt], cc[nt][bt], 0, 0, 0);
            }
        }
        // no barrier: h2/d2 go to separate buffers
        if (wv < 8) {   // h-wave epilogue: silu -> h2s/d2s, packed b64 stores (batch row = lane r)
#pragma unroll
            for (int nt = 0; nt < 2; ++nt) {
                const f32x4* bp2 = (const f32x4*)&b2l[n0w + nt * 16 + 4 * g];
                const f32x4 bb = bp2[opq];               // per-stage ds_read_b128, not a register
#pragma unroll
                for (int bt = 0; bt < 2; ++bt) {
                    float h[4], d[4];
#pragma unroll
                    for (int q = 0; q < 4; ++q) silu_both(cc[nt][bt][q] + bb[q], h[q], d[q]);
                    const int row = bt * 16 + r;
                    const int col = (n0w + nt * 16 + 4 * g) ^ swr;
                    u32x2 hv  = { packtr(h[0], h[1]), packtr(h[2], h[3]) };
                    u32x2 dv2 = { packtr(d[0], d[1]), packtr(d[2], d[3]) };
                    *(u32x2*)&h2s[row][col] = hv;
                    *(u32x2*)&d2s[row][col] = dv2;
                }
            }
        }
        __syncthreads();   // B4: h2/d2 ready

        if (wv < 2) {
            // ---------- phase 3 (operand-swapped): fz^T[i][b] = W3^T @ h2^T, K=256,
            //            dual accumulator chains; in-register RK4; packed zb write ----------
            const unsigned short* h2row = &h2s[wv * 16 + r][0];
            const unsigned short* w3row = &w3t[r][0];
            f32x4 c3a = {0.f, 0.f, 0.f, 0.f}, c3b = {0.f, 0.f, 0.f, 0.f};
#pragma unroll
            for (int kt = 0; kt < 8; ++kt) {
                const bf16x8 a3  = *(const bf16x8*)(w3row + kt * 32 + g8);
                const bf16x8 bf3 = *(const bf16x8*)(h2row + kt * 32 + goff);
                if (kt & 1) c3b = __builtin_amdgcn_mfma_f32_16x16x32_bf16(a3, bf3, c3b, 0, 0, 0);
                else        c3a = __builtin_amdgcn_mfma_f32_16x16x32_bf16(a3, bf3, c3a, 0, 0, 0);
            }
            const f32x4* bp3 = (const f32x4*)&b3l[4 * g];
            const f32x4 b3v = bp3[opq];                  // per-stage reload, not a register
            const float coef = (s == 2) ? dt : 0.5f * dt;
            float zn[4];
#pragma unroll
            for (int q = 0; q < 4; ++q) {
                const float fz = c3a[q] + c3b[q] + b3v[q];
                za4[q] = fmaf(wst, fz, za4[q]);
                if (s < 3) zn[q] = fmaf(coef, fz, zb4[q]);
                else { zb4[q] = fmaf(dt6, za4[q], zb4[q]); zn[q] = zb4[q]; za4[q] = 0.0f; }
            }
            u32x2 pz = { (unsigned)f2bf(zn[0]) | ((unsigned)f2bf(zn[1]) << 16),
                         (unsigned)f2bf(zn[2]) | ((unsigned)f2bf(zn[3]) << 16) };
            *(u32x2*)&zb[wv * 16 + r][4 * g] = pz;
            if (wv == 0 && lane < TILE_B) {      // publish t for next stage
                const int it1 = it + 1;
                const int s1 = it1 & 3;
                const float t1 = dt * (float)(it1 >> 2) + ((s1 == 0) ? 0.0f : (s1 == 3) ? dt : 0.5f * dt);
                zb[lane][16] = f2bf(t1);
            }
        } else if (wv >= 8) {
            // ---------- v-waves: div_b = sum_n d2[b][n]*v[n][b]; batch lane-local.
            //            4 packed b64 reads + 16 fma + 4 shfl ----------
            float p0 = 0.0f, p1 = 0.0f;
#pragma unroll
            for (int nt = 0; nt < 2; ++nt)
#pragma unroll
                for (int bt = 0; bt < 2; ++bt) {
                    const int row = bt * 16 + r;
                    const int col = (n0w + nt * 16 + 4 * g) ^ swr;
                    const u32x2 du = *(const u32x2*)&d2s[row][col];
                    float pp = (bt == 0) ? p0 : p1;
                    pp = fmaf(bfw_lo(du[0]), cc[nt][bt][0], pp);
                    pp = fmaf(bfw_hi(du[0]), cc[nt][bt][1], pp);
                    pp = fmaf(bfw_lo(du[1]), cc[nt][bt][2], pp);
                    pp = fmaf(bfw_hi(du[1]), cc[nt][bt][3], pp);
                    if (bt == 0) p0 = pp; else p1 = pp;
                }
            p0 += __shfl_xor(p0, 16, 64);
            p0 += __shfl_xor(p0, 32, 64);
            p1 += __shfl_xor(p1, 16, 64);
            p1 += __shfl_xor(p1, 32, 64);
            if (g < 2) divp[wv - 8][g * 16 + r] = g ? p1 : p0;
        }
        // (loop-top barrier covers zb, t-col and divp)
    }

    // ---------- epilogue ----------
    __syncthreads();
    if (wv == 8 && lane < TILE_B) {   // flush last stage (s=3, weight 1) and publish logp
        float dv = 0.0f;
#pragma unroll
        for (int w = 0; w < 8; ++w) dv += divp[w][lane];
        lacc -= dv;
        logp = fmaf(dt6, lacc, logp);
        divp[0][lane] = logp;
    }
    __syncthreads();
    if (wv < 2) {
        float ss = zb4[0] * zb4[0] + zb4[1] * zb4[1] + zb4[2] * zb4[2] + zb4[3] * zb4[3];
        ss += __shfl_xor(ss, 16, 64);
        ss += __shfl_xor(ss, 32, 64);
        if (g == 0) {
            const int row = wv * 16 + r;
            out[b0 + row] = -0.5f * (ss + (float)DIM * 1.8378770664093453f) - divp[0][row];
        }
    }
}

extern "C" void kernel_launch(void* const* d_in, const int* in_sizes, int n_in,
                              void* d_out, int out_size, void* d_ws, size_t ws_size,
                              hipStream_t stream) {
    (void)in_sizes; (void)n_in; (void)out_size; (void)ws_size;
    const float* x  = (const float*)d_in[0];
    const float* W1 = (const float*)d_in[1];
    const float* b1 = (const float*)d_in[2];
    const float* W2 = (const float*)d_in[3];
    const float* b2 = (const float*)d_in[4];
    const float* W3 = (const float*)d_in[5];
    const float* b3 = (const float*)d_in[6];
    unsigned short* w2t = (unsigned short*)d_ws;               // 128 KB
    unsigned short* mt  = w2t + HID * HID;                     // 128 KB

    cnf_setup<<<HID, HID, 0, stream>>>(W1, W2, W3, w2t, mt);
    cnf_main<<<8192 / TILE_B, NTHR, 0, stream>>>(x, W1, b1, b2, b3, w2t, mt, W3, (float*)d_out);
}